// Round 2
// baseline (1584.256 us; speedup 1.0000x reference)
//
#include <hip/hip_runtime.h>
#include <math.h>

#define BB 2
#define SS 2048
#define EE 1024
#define HH 16

// ---------------------------------------------------------------------------
// C[M][N] = A[M][K] @ W[K][N] + bias[N]    (fp32, 64x64 tile, 4x4 per thread)
// ---------------------------------------------------------------------------
__global__ __launch_bounds__(256) void gemm_bias(
    const float* __restrict__ A, const float* __restrict__ W,
    const float* __restrict__ bias, float* __restrict__ C,
    int M, int N, int K)
{
  __shared__ float As[16][68];   // transposed A tile [k][m], padded
  __shared__ float Bs[16][68];   // B tile [k][n], padded

  const int t  = threadIdx.x;
  const int tx = t & 15, ty = t >> 4;
  const int n0 = blockIdx.x * 64, m0 = blockIdx.y * 64;

  const int arow = t >> 2,  ak = (t & 3) * 4;
  const int bk   = t >> 4,  bc = (t & 15) * 4;
  const float* Ap = A + (size_t)(m0 + arow) * K + ak;
  const float* Wp = W + (size_t)bk * N + n0 + bc;

  float acc[4][4] = {};

  for (int k0 = 0; k0 < K; k0 += 16) {
    float4 ga = *(const float4*)(Ap + k0);
    float4 gb = *(const float4*)(Wp + (size_t)k0 * N);
    As[ak + 0][arow] = ga.x;
    As[ak + 1][arow] = ga.y;
    As[ak + 2][arow] = ga.z;
    As[ak + 3][arow] = ga.w;
    *(float4*)&Bs[bk][bc] = gb;
    __syncthreads();
#pragma unroll
    for (int kk = 0; kk < 16; ++kk) {
      float a[4], b[4];
      *(float4*)a = *(const float4*)&As[kk][ty * 4];
      *(float4*)b = *(const float4*)&Bs[kk][tx * 4];
#pragma unroll
      for (int i = 0; i < 4; ++i)
#pragma unroll
        for (int j = 0; j < 4; ++j)
          acc[i][j] = fmaf(a[i], b[j], acc[i][j]);
    }
    __syncthreads();
  }

  const float4 bv = *(const float4*)(bias + n0 + tx * 4);
#pragma unroll
  for (int i = 0; i < 4; ++i) {
    float4 o;
    o.x = acc[i][0] + bv.x;
    o.y = acc[i][1] + bv.y;
    o.z = acc[i][2] + bv.z;
    o.w = acc[i][3] + bv.w;
    *(float4*)(C + (size_t)(m0 + ty * 4 + i) * N + n0 + tx * 4) = o;
  }
}

// ---------------------------------------------------------------------------
// Fused attention: qkv (4096 x 3072) -> aout (4096 x 1024), token-major.
// Faithful quirk: masked scores are set to 1e-9 (NOT -inf) before softmax.
// Mask is int32 (harness stages jnp bool as int): nonzero = masked.
// Layout: 256 threads = 4 waves; per wave: 8 dim-groups (8 dims each) x
// 8 row-groups; each lane owns 4 consecutive q-rows -> 128 rows / block.
// K/V tiles of 64 rows staged in LDS (padded to 68 floats/row).
// ---------------------------------------------------------------------------
__global__ __launch_bounds__(256) void attn_fused(
    const float* __restrict__ qkv, const int* __restrict__ mask,
    float* __restrict__ aout)
{
  __shared__ float Kds[64][68];
  __shared__ float Vds[64][68];

  const int t    = threadIdx.x;
  const int lane = t & 63, wave = t >> 6;
  const int dimg = lane & 7, rg = lane >> 3;

  const int b = blockIdx.y >> 4, h = blockIdx.y & 15;
  const int row0 = blockIdx.x * 128 + wave * 32 + rg * 4;

  float q[4][8], o[4][8], m[4], l[4];
#pragma unroll
  for (int r = 0; r < 4; ++r) {
    const float* qp =
        qkv + (size_t)(b * SS + row0 + r) * 3072 + h * 64 + dimg * 8;
    float4 q0 = *(const float4*)qp;
    float4 q1 = *(const float4*)(qp + 4);
    // pre-scale by 1/sqrt(D) = 1/8
    q[r][0] = q0.x * 0.125f; q[r][1] = q0.y * 0.125f;
    q[r][2] = q0.z * 0.125f; q[r][3] = q0.w * 0.125f;
    q[r][4] = q1.x * 0.125f; q[r][5] = q1.y * 0.125f;
    q[r][6] = q1.z * 0.125f; q[r][7] = q1.w * 0.125f;
    m[r] = -INFINITY;
    l[r] = 0.0f;
#pragma unroll
    for (int j = 0; j < 8; ++j) o[r][j] = 0.0f;
  }

  const int* mp = mask + ((size_t)b * SS + row0) * SS;

  for (int kt = 0; kt < SS; kt += 64) {
    // stage K (64x64) and V (64x64) tiles
#pragma unroll
    for (int i = 0; i < 4; ++i) {
      int idx = t + i * 256;
      int r = idx >> 4, c = (idx & 15) * 4;
      const float* src =
          qkv + (size_t)(b * SS + kt + r) * 3072 + EE + h * 64 + c;
      *(float4*)&Kds[r][c] = *(const float4*)src;
      *(float4*)&Vds[r][c] = *(const float4*)(src + EE);
    }
    __syncthreads();

    for (int kk4 = 0; kk4 < 64; kk4 += 4) {
      int4 mw[4];
#pragma unroll
      for (int r = 0; r < 4; ++r)
        mw[r] = *(const int4*)(mp + (size_t)r * SS + kt + kk4);

#pragma unroll
      for (int u = 0; u < 4; ++u) {
        const int kk = kk4 + u;
        float kv[8];
        *(float4*)&kv[0] = *(const float4*)&Kds[kk][dimg * 8];
        *(float4*)&kv[4] = *(const float4*)&Kds[kk][dimg * 8 + 4];

        float s[4] = {0.f, 0.f, 0.f, 0.f};
#pragma unroll
        for (int j = 0; j < 8; ++j)
#pragma unroll
          for (int r = 0; r < 4; ++r)
            s[r] = fmaf(q[r][j], kv[j], s[r]);

#pragma unroll
        for (int r = 0; r < 4; ++r) {
          s[r] += __shfl_xor(s[r], 1);
          s[r] += __shfl_xor(s[r], 2);
          s[r] += __shfl_xor(s[r], 4);
          const int mv = (u == 0) ? mw[r].x
                       : (u == 1) ? mw[r].y
                       : (u == 2) ? mw[r].z
                                  : mw[r].w;
          if (mv != 0) s[r] = 1e-9f;  // faithful quirk: 1e-9, not -inf
        }

        float vv[8];
        *(float4*)&vv[0] = *(const float4*)&Vds[kk][dimg * 8];
        *(float4*)&vv[4] = *(const float4*)&Vds[kk][dimg * 8 + 4];

#pragma unroll
        for (int r = 0; r < 4; ++r) {
          if (s[r] > m[r]) {                    // rarely-taken rescale
            float c = __expf(m[r] - s[r]);
            l[r] *= c;
#pragma unroll
            for (int j = 0; j < 8; ++j) o[r][j] *= c;
            m[r] = s[r];
          }
          float p = __expf(s[r] - m[r]);
          l[r] += p;
#pragma unroll
          for (int j = 0; j < 8; ++j) o[r][j] = fmaf(p, vv[j], o[r][j]);
        }
      }
    }
    __syncthreads();
  }

#pragma unroll
  for (int r = 0; r < 4; ++r) {
    float inv = 1.0f / l[r];
    float* op = aout + (size_t)(b * SS + row0 + r) * EE + h * 64 + dimg * 8;
    float4 o0, o1;
    o0.x = o[r][0] * inv; o0.y = o[r][1] * inv;
    o0.z = o[r][2] * inv; o0.w = o[r][3] * inv;
    o1.x = o[r][4] * inv; o1.y = o[r][5] * inv;
    o1.z = o[r][6] * inv; o1.w = o[r][7] * inv;
    *(float4*)op = o0;
    *(float4*)(op + 4) = o1;
  }
}

// ---------------------------------------------------------------------------
extern "C" void kernel_launch(void* const* d_in, const int* in_sizes, int n_in,
                              void* d_out, int out_size, void* d_ws,
                              size_t ws_size, hipStream_t stream)
{
  (void)in_sizes; (void)n_in; (void)out_size; (void)ws_size;
  const float* x   = (const float*)d_in[0];
  const int* mask  = (const int*)d_in[1];   // jnp bool staged as int32
  const float* wk  = (const float*)d_in[2];
  const float* wb  = (const float*)d_in[3];
  const float* fck = (const float*)d_in[4];
  const float* fcb = (const float*)d_in[5];
  float* out       = (float*)d_out;

  float* qkv  = (float*)d_ws;                       // 4096*3072 f32 = 50.3 MB
  float* aout = qkv + (size_t)4096 * 3072;          // 4096*1024 f32 = 16.8 MB

  // qkv = x @ w_kernel + w_bias
  gemm_bias<<<dim3(3072 / 64, 4096 / 64), 256, 0, stream>>>(
      x, wk, wb, qkv, 4096, 3072, 1024);
  // fused masked softmax attention -> token-major (b, s, h*64+d)
  attn_fused<<<dim3(SS / 128, BB * HH), 256, 0, stream>>>(qkv, mask, aout);
  // out = aout @ fc_kernel + fc_bias
  gemm_bias<<<dim3(1024 / 64, 4096 / 64), 256, 0, stream>>>(
      aout, fck, fcb, out, 4096, 1024, 1024);
}

// Round 3
// 693.496 us; speedup vs baseline: 2.2844x; 2.2844x over previous
//
#include <hip/hip_runtime.h>
#include <math.h>

#define BB 2
#define SS 2048
#define EE 1024
#define HH 16

typedef __attribute__((ext_vector_type(8))) __bf16 bf16x8;
typedef __attribute__((ext_vector_type(4))) __bf16 bf16x4;
typedef __attribute__((ext_vector_type(4))) float f32x4;

static __device__ __forceinline__ unsigned short bfbits(float f) {
  __bf16 b = (__bf16)f;  // RNE
  return __builtin_bit_cast(unsigned short, b);
}

// ---------------------------------------------------------------------------
// GEMM1: qkv = x @ w_kernel + w_bias, fp32 compute.
// Epilogue: cols [0,2048) -> qkbuf bf16 [token][2048] (q then k);
//           cols [2048,3072) -> vT bf16 [(b*16+h)*64+d][s]  (V transposed).
// ---------------------------------------------------------------------------
__global__ __launch_bounds__(256) void gemm_qkv(
    const float* __restrict__ A, const float* __restrict__ W,
    const float* __restrict__ bias, __bf16* __restrict__ qkbuf,
    __bf16* __restrict__ vT)
{
  __shared__ float As[16][68];
  __shared__ float Bs[16][68];
  const int K = 1024, N = 3072;

  const int t  = threadIdx.x;
  const int tx = t & 15, ty = t >> 4;
  const int n0 = blockIdx.x * 64, m0 = blockIdx.y * 64;

  const int arow = t >> 2,  ak = (t & 3) * 4;
  const int bk   = t >> 4,  bc = (t & 15) * 4;
  const float* Ap = A + (size_t)(m0 + arow) * K + ak;
  const float* Wp = W + (size_t)bk * N + n0 + bc;

  float acc[4][4] = {};

  for (int k0 = 0; k0 < K; k0 += 16) {
    float4 ga = *(const float4*)(Ap + k0);
    float4 gb = *(const float4*)(Wp + (size_t)k0 * N);
    As[ak + 0][arow] = ga.x;
    As[ak + 1][arow] = ga.y;
    As[ak + 2][arow] = ga.z;
    As[ak + 3][arow] = ga.w;
    *(float4*)&Bs[bk][bc] = gb;
    __syncthreads();
#pragma unroll
    for (int kk = 0; kk < 16; ++kk) {
      float a[4], b[4];
      *(float4*)a = *(const float4*)&As[kk][ty * 4];
      *(float4*)b = *(const float4*)&Bs[kk][tx * 4];
#pragma unroll
      for (int i = 0; i < 4; ++i)
#pragma unroll
        for (int j = 0; j < 4; ++j)
          acc[i][j] = fmaf(a[i], b[j], acc[i][j]);
    }
    __syncthreads();
  }

  float bv[4];
  *(float4*)bv = *(const float4*)(bias + n0 + tx * 4);

  if (n0 < 2048) {
#pragma unroll
    for (int i = 0; i < 4; ++i) {
      const int token = m0 + ty * 4 + i;
      bf16x4 s4;
      s4[0] = (__bf16)(acc[i][0] + bv[0]);
      s4[1] = (__bf16)(acc[i][1] + bv[1]);
      s4[2] = (__bf16)(acc[i][2] + bv[2]);
      s4[3] = (__bf16)(acc[i][3] + bv[3]);
      *(bf16x4*)(qkbuf + (size_t)token * 2048 + n0 + tx * 4) = s4;
    }
  } else {
    const int hv = (n0 - 2048) >> 6;          // head (n0 is 64-aligned)
    const int dbase = (n0 & 63) + tx * 4;     // = tx*4
#pragma unroll
    for (int i = 0; i < 4; ++i) {
      const int token = m0 + ty * 4 + i;
      const int bq = token >> 11, sq = token & 2047;
#pragma unroll
      for (int j = 0; j < 4; ++j) {
        vT[((size_t)(bq * 16 + hv) * 64 + dbase + j) * SS + sq] =
            (__bf16)(acc[i][j] + bv[j]);
      }
    }
  }
}

// ---------------------------------------------------------------------------
// MFMA attention. Grid (32 q-tiles, 32 b*h); 256 thr = 4 waves x 16 q-rows.
// Swapped QK^T: S^T = mfma(K, Q) -> lane holds 8 keys for q = lane&15.
// No max-subtraction (scores bounded ~|7|); softmax = exp(s)/sum.
// P -> per-wave LDS -> PV A-frag; V staged from pre-transposed vT.
// ---------------------------------------------------------------------------
__global__ __launch_bounds__(256) void attn_mfma(
    const __bf16* __restrict__ qkbuf, const __bf16* __restrict__ vT,
    const int* __restrict__ mask, float* __restrict__ aout)
{
  __shared__ __bf16 Kt[32][72];        // [key][d], pad 72 (144B rows)
  __shared__ __bf16 Vt[64][40];        // [d][key], pad 40 (80B rows)
  __shared__ __bf16 Pl[4][16][40];     // per-wave [q][key]
  __shared__ float  Ll[4][16];

  const int t = threadIdx.x;
  const int w = t >> 6, l = t & 63, l15 = l & 15, l4 = l >> 4;
  const int bh = blockIdx.y, b = bh >> 4, h = bh & 15;
  const int q0 = blockIdx.x * 64 + w * 16;   // this wave's first q row
  const int qtok = b * SS + q0 + l15;

  // Q B-fragments (held in regs): Q[q=l15][d = c*32 + l4*8 + i]
  const bf16x8 bq0 = *(const bf16x8*)(qkbuf + (size_t)qtok * 2048 + h * 64 + l4 * 8);
  const bf16x8 bq1 = *(const bf16x8*)(qkbuf + (size_t)qtok * 2048 + h * 64 + 32 + l4 * 8);

  f32x4 acc[4] = {{0.f,0.f,0.f,0.f},{0.f,0.f,0.f,0.f},
                  {0.f,0.f,0.f,0.f},{0.f,0.f,0.f,0.f}};
  float lsum = 0.f;

  const int* mrow = mask + ((size_t)b * SS + q0 + l15) * SS;

  // staging assignments
  const int krow = t >> 3, kcb = (t & 7) * 8;
  const __bf16* ksrc =
      qkbuf + (size_t)(b * SS + krow) * 2048 + 1024 + h * 64 + kcb;
  const int vd = t >> 2, vkb = (t & 3) * 8;
  const __bf16* vsrc = vT + ((size_t)bh * 64 + vd) * SS + vkb;

  for (int kt = 0; kt < SS; kt += 32) {
    *(bf16x8*)&Kt[krow][kcb] = *(const bf16x8*)(ksrc + (size_t)kt * 2048);
    *(bf16x8*)&Vt[vd][vkb]   = *(const bf16x8*)(vsrc + kt);
    __syncthreads();

    float p[2][4];
#pragma unroll
    for (int g = 0; g < 2; ++g) {
      const int4 mv = *(const int4*)(mrow + kt + g * 16 + l4 * 4);
      const bf16x8 a0 = *(const bf16x8*)&Kt[g * 16 + l15][l4 * 8];
      const bf16x8 a1 = *(const bf16x8*)&Kt[g * 16 + l15][32 + l4 * 8];
      f32x4 S = __builtin_amdgcn_mfma_f32_16x16x32_bf16(
          a0, bq0, (f32x4){0.f, 0.f, 0.f, 0.f}, 0, 0, 0);
      S = __builtin_amdgcn_mfma_f32_16x16x32_bf16(a1, bq1, S, 0, 0, 0);
      // scale 1/8, mask quirk (1e-9, not -inf), exp (no max-subtract)
      p[g][0] = __expf(mv.x ? 1e-9f : S[0] * 0.125f);
      p[g][1] = __expf(mv.y ? 1e-9f : S[1] * 0.125f);
      p[g][2] = __expf(mv.z ? 1e-9f : S[2] * 0.125f);
      p[g][3] = __expf(mv.w ? 1e-9f : S[3] * 0.125f);
      unsigned int pk0 =
          (unsigned)bfbits(p[g][0]) | ((unsigned)bfbits(p[g][1]) << 16);
      unsigned int pk1 =
          (unsigned)bfbits(p[g][2]) | ((unsigned)bfbits(p[g][3]) << 16);
      unsigned int* dst = (unsigned int*)&Pl[w][l15][g * 16 + l4 * 4];
      dst[0] = pk0;
      dst[1] = pk1;
    }
    float ps = ((p[0][0] + p[0][1]) + (p[0][2] + p[0][3])) +
               ((p[1][0] + p[1][1]) + (p[1][2] + p[1][3]));
    ps += __shfl_xor(ps, 16);
    ps += __shfl_xor(ps, 32);
    lsum += ps;

    // PV: A = P[q=l15][key=l4*8+i], B = V[key][d] from Vt rows
    const bf16x8 pa = *(const bf16x8*)&Pl[w][l15][l4 * 8];
#pragma unroll
    for (int dg = 0; dg < 4; ++dg) {
      const bf16x8 vb = *(const bf16x8*)&Vt[dg * 16 + l15][l4 * 8];
      acc[dg] = __builtin_amdgcn_mfma_f32_16x16x32_bf16(pa, vb, acc[dg], 0, 0, 0);
    }
    __syncthreads();
  }

  if (l4 == 0) Ll[w][l15] = lsum;
  __syncthreads();

#pragma unroll
  for (int r = 0; r < 4; ++r) {
    const float inv = 1.0f / Ll[w][l4 * 4 + r];
    const int tok = b * SS + q0 + l4 * 4 + r;
    float* op = aout + (size_t)tok * EE + h * 64 + l15;
#pragma unroll
    for (int dg = 0; dg < 4; ++dg) op[dg * 16] = acc[dg][r] * inv;
  }
}

// ---------------------------------------------------------------------------
// GEMM2 (unchanged fp32): out = aout @ fc_kernel + fc_bias
// ---------------------------------------------------------------------------
__global__ __launch_bounds__(256) void gemm_bias(
    const float* __restrict__ A, const float* __restrict__ W,
    const float* __restrict__ bias, float* __restrict__ C,
    int M, int N, int K)
{
  __shared__ float As[16][68];
  __shared__ float Bs[16][68];

  const int t  = threadIdx.x;
  const int tx = t & 15, ty = t >> 4;
  const int n0 = blockIdx.x * 64, m0 = blockIdx.y * 64;

  const int arow = t >> 2,  ak = (t & 3) * 4;
  const int bk   = t >> 4,  bc = (t & 15) * 4;
  const float* Ap = A + (size_t)(m0 + arow) * K + ak;
  const float* Wp = W + (size_t)bk * N + n0 + bc;

  float acc[4][4] = {};

  for (int k0 = 0; k0 < K; k0 += 16) {
    float4 ga = *(const float4*)(Ap + k0);
    float4 gb = *(const float4*)(Wp + (size_t)k0 * N);
    As[ak + 0][arow] = ga.x;
    As[ak + 1][arow] = ga.y;
    As[ak + 2][arow] = ga.z;
    As[ak + 3][arow] = ga.w;
    *(float4*)&Bs[bk][bc] = gb;
    __syncthreads();
#pragma unroll
    for (int kk = 0; kk < 16; ++kk) {
      float a[4], b[4];
      *(float4*)a = *(const float4*)&As[kk][ty * 4];
      *(float4*)b = *(const float4*)&Bs[kk][tx * 4];
#pragma unroll
      for (int i = 0; i < 4; ++i)
#pragma unroll
        for (int j = 0; j < 4; ++j)
          acc[i][j] = fmaf(a[i], b[j], acc[i][j]);
    }
    __syncthreads();
  }

  const float4 bv = *(const float4*)(bias + n0 + tx * 4);
#pragma unroll
  for (int i = 0; i < 4; ++i) {
    float4 o;
    o.x = acc[i][0] + bv.x;
    o.y = acc[i][1] + bv.y;
    o.z = acc[i][2] + bv.z;
    o.w = acc[i][3] + bv.w;
    *(float4*)(C + (size_t)(m0 + ty * 4 + i) * N + n0 + tx * 4) = o;
  }
}

// ---------------------------------------------------------------------------
extern "C" void kernel_launch(void* const* d_in, const int* in_sizes, int n_in,
                              void* d_out, int out_size, void* d_ws,
                              size_t ws_size, hipStream_t stream)
{
  (void)in_sizes; (void)n_in; (void)out_size; (void)ws_size;
  const float* x   = (const float*)d_in[0];
  const int* mask  = (const int*)d_in[1];   // jnp bool staged as int32
  const float* wk  = (const float*)d_in[2];
  const float* wb  = (const float*)d_in[3];
  const float* fck = (const float*)d_in[4];
  const float* fcb = (const float*)d_in[5];
  float* out       = (float*)d_out;

  char* ws = (char*)d_ws;
  __bf16* qkbuf = (__bf16*)ws;                                  // 16.8 MB
  __bf16* vT    = (__bf16*)(ws + (size_t)4096 * 2048 * 2);      //  8.4 MB
  float*  aout  = (float*)(ws + (size_t)4096 * 2048 * 2 +
                                (size_t)2048 * 2048 * 2);       // 16.8 MB

  gemm_qkv<<<dim3(3072 / 64, 4096 / 64), 256, 0, stream>>>(
      x, wk, wb, qkbuf, vT);
  attn_mfma<<<dim3(SS / 64, BB * HH), 256, 0, stream>>>(
      qkbuf, vT, mask, aout);
  gemm_bias<<<dim3(1024 / 64, 4096 / 64), 256, 0, stream>>>(
      aout, fck, fcb, out, 4096, 1024, 1024);
}

// Round 4
// 291.634 us; speedup vs baseline: 5.4323x; 2.3780x over previous
//
#include <hip/hip_runtime.h>
#include <math.h>

#define BB 2
#define SS 2048
#define EE 1024
#define HH 16

typedef _Float16 f16;
typedef __attribute__((ext_vector_type(8))) _Float16 f16x8;
typedef __attribute__((ext_vector_type(4))) _Float16 f16x4;
typedef __attribute__((ext_vector_type(4))) float f32x4;

static __device__ __forceinline__ unsigned short hbits(float f) {
  f16 h = (f16)f;
  return __builtin_bit_cast(unsigned short, h);
}

// ---------------------------------------------------------------------------
// fp32 -> fp16 elementwise (n % 8 == 0)
// ---------------------------------------------------------------------------
__global__ __launch_bounds__(256) void cvt_f32_f16(
    const float* __restrict__ in, f16* __restrict__ out, int n)
{
  int i = (blockIdx.x * 256 + threadIdx.x) * 8;
  if (i >= n) return;
  float4 a = *(const float4*)(in + i);
  float4 b = *(const float4*)(in + i + 4);
  f16x8 o;
  o[0] = (f16)a.x; o[1] = (f16)a.y; o[2] = (f16)a.z; o[3] = (f16)a.w;
  o[4] = (f16)b.x; o[5] = (f16)b.y; o[6] = (f16)b.z; o[7] = (f16)b.w;
  *(f16x8*)(out + i) = o;
}

// ---------------------------------------------------------------------------
// out[n][k] = (f16) in[k][n]   (K x N fp32 -> N x K fp16), 64x64 LDS tiles
// ---------------------------------------------------------------------------
__global__ __launch_bounds__(256) void transpose_cvt(
    const float* __restrict__ in, f16* __restrict__ out, int K, int N)
{
  __shared__ float T[64][65];
  const int k0 = blockIdx.y * 64, n0 = blockIdx.x * 64;
  const int tr = threadIdx.x >> 4, tc = (threadIdx.x & 15) * 4;
#pragma unroll
  for (int i = 0; i < 4; ++i) {
    int r = tr + i * 16;
    *(float4*)&T[r][tc] = *(const float4*)(in + (size_t)(k0 + r) * N + n0 + tc);
  }
  __syncthreads();
#pragma unroll
  for (int i = 0; i < 4; ++i) {
    int nl = tr + i * 16;
    f16x4 v;
    v[0] = (f16)T[tc + 0][nl];
    v[1] = (f16)T[tc + 1][nl];
    v[2] = (f16)T[tc + 2][nl];
    v[3] = (f16)T[tc + 3][nl];
    *(f16x4*)(out + (size_t)(n0 + nl) * K + k0 + tc) = v;
  }
}

// ---------------------------------------------------------------------------
// MFMA fp16 GEMM: C[M][N] = A[M][K] @ Bt[N][K]^T + bias.
// 128x128 tile, 256 thr = 4 waves (2x2), each wave 64x64 = 4x4 16x16 frags.
// mode 0: qkv epilogue -> oQK f16 [token][2048] (n<2048), vT f16 (n>=2048).
// mode 1: fp32 out + bias.
// ---------------------------------------------------------------------------
__global__ __launch_bounds__(256) void gemm_f16(
    const f16* __restrict__ A, const f16* __restrict__ Bt,
    const float* __restrict__ bias, int M, int N, int K, int mode,
    f16* __restrict__ oQK, f16* __restrict__ oVT, float* __restrict__ oF32)
{
  __shared__ f16 Ah[128][36];
  __shared__ f16 Bh[128][36];

  const int t = threadIdx.x;
  const int l = t & 63, w = t >> 6;
  const int l15 = l & 15, l4 = l >> 4;
  const int wr = w >> 1, wc = w & 1;
  const int n0 = blockIdx.x * 128, m0 = blockIdx.y * 128;

  const int srow = t >> 1, soff = (t & 1) * 16;
  const f16* Ap = A + (size_t)(m0 + srow) * K + soff;
  const f16* Bp = Bt + (size_t)(n0 + srow) * K + soff;

  f32x4 acc[4][4] = {};

  f16x8 ra0 = *(const f16x8*)(Ap);
  f16x8 ra1 = *(const f16x8*)(Ap + 8);
  f16x8 rb0 = *(const f16x8*)(Bp);
  f16x8 rb1 = *(const f16x8*)(Bp + 8);

  for (int k0 = 0; k0 < K; k0 += 32) {
    __syncthreads();
    *(f16x8*)&Ah[srow][soff]     = ra0;
    *(f16x8*)&Ah[srow][soff + 8] = ra1;
    *(f16x8*)&Bh[srow][soff]     = rb0;
    *(f16x8*)&Bh[srow][soff + 8] = rb1;
    __syncthreads();
    if (k0 + 32 < K) {
      ra0 = *(const f16x8*)(Ap + k0 + 32);
      ra1 = *(const f16x8*)(Ap + k0 + 40);
      rb0 = *(const f16x8*)(Bp + k0 + 32);
      rb1 = *(const f16x8*)(Bp + k0 + 40);
    }
    f16x8 af[4], bf[4];
#pragma unroll
    for (int mr = 0; mr < 4; ++mr)
      af[mr] = *(const f16x8*)&Ah[wr * 64 + mr * 16 + l15][l4 * 8];
#pragma unroll
    for (int nr = 0; nr < 4; ++nr)
      bf[nr] = *(const f16x8*)&Bh[wc * 64 + nr * 16 + l15][l4 * 8];
#pragma unroll
    for (int mr = 0; mr < 4; ++mr)
#pragma unroll
      for (int nr = 0; nr < 4; ++nr)
        acc[mr][nr] = __builtin_amdgcn_mfma_f32_16x16x32_f16(
            af[mr], bf[nr], acc[mr][nr], 0, 0, 0);
  }

  if (mode == 1) {
#pragma unroll
    for (int nr = 0; nr < 4; ++nr) {
      const int n = n0 + wc * 64 + nr * 16 + l15;
      const float bv = bias[n];
#pragma unroll
      for (int mr = 0; mr < 4; ++mr)
#pragma unroll
        for (int j = 0; j < 4; ++j) {
          const int m = m0 + wr * 64 + mr * 16 + l4 * 4 + j;
          oF32[(size_t)m * N + n] = acc[mr][nr][j] + bv;
        }
    }
  } else {
#pragma unroll
    for (int nr = 0; nr < 4; ++nr) {
      const int n = n0 + wc * 64 + nr * 16 + l15;
      const float bv = bias[n];
      if (n < 2048) {
#pragma unroll
        for (int mr = 0; mr < 4; ++mr)
#pragma unroll
          for (int j = 0; j < 4; ++j) {
            const int m = m0 + wr * 64 + mr * 16 + l4 * 4 + j;
            oQK[(size_t)m * 2048 + n] = (f16)(acc[mr][nr][j] + bv);
          }
      } else {
        const int hh = (n - 2048) >> 6;
        const int d = (n - 2048) & 63;
#pragma unroll
        for (int mr = 0; mr < 4; ++mr) {
          const int tok0 = m0 + wr * 64 + mr * 16 + l4 * 4;
          const int bq = tok0 >> 11, sq = tok0 & 2047;
          f16x4 v;
          v[0] = (f16)(acc[mr][nr][0] + bv);
          v[1] = (f16)(acc[mr][nr][1] + bv);
          v[2] = (f16)(acc[mr][nr][2] + bv);
          v[3] = (f16)(acc[mr][nr][3] + bv);
          *(f16x4*)(oVT + ((size_t)(bq * 16 + hh) * 64 + d) * SS + sq) = v;
        }
      }
    }
  }
}

// ---------------------------------------------------------------------------
// MFMA attention (fp16). Grid (32 q-tiles, 32 b*h); 4 waves x 16 q-rows.
// Swapped QK^T; no max-subtraction; mask quirk (1e-9, not -inf).
// Writes aout as f16 [token][1024].
// ---------------------------------------------------------------------------
__global__ __launch_bounds__(256) void attn_mfma(
    const f16* __restrict__ qkbuf, const f16* __restrict__ vT,
    const int* __restrict__ mask, f16* __restrict__ aout)
{
  __shared__ f16 Kt[32][72];
  __shared__ f16 Vt[64][40];
  __shared__ f16 Pl[4][16][40];
  __shared__ float Ll[4][16];

  const int t = threadIdx.x;
  const int w = t >> 6, l = t & 63, l15 = l & 15, l4 = l >> 4;
  const int bh = blockIdx.y, b = bh >> 4, h = bh & 15;
  const int q0 = blockIdx.x * 64 + w * 16;
  const int qtok = b * SS + q0 + l15;

  const f16x8 bq0 = *(const f16x8*)(qkbuf + (size_t)qtok * 2048 + h * 64 + l4 * 8);
  const f16x8 bq1 = *(const f16x8*)(qkbuf + (size_t)qtok * 2048 + h * 64 + 32 + l4 * 8);

  f32x4 acc[4] = {{0.f,0.f,0.f,0.f},{0.f,0.f,0.f,0.f},
                  {0.f,0.f,0.f,0.f},{0.f,0.f,0.f,0.f}};
  float lsum = 0.f;

  const int* mrow = mask + ((size_t)b * SS + q0 + l15) * SS;

  const int krow = t >> 3, kcb = (t & 7) * 8;
  const f16* ksrc = qkbuf + (size_t)(b * SS + krow) * 2048 + 1024 + h * 64 + kcb;
  const int vd = t >> 2, vkb = (t & 3) * 8;
  const f16* vsrc = vT + ((size_t)bh * 64 + vd) * SS + vkb;

  for (int kt = 0; kt < SS; kt += 32) {
    *(f16x8*)&Kt[krow][kcb] = *(const f16x8*)(ksrc + (size_t)kt * 2048);
    *(f16x8*)&Vt[vd][vkb]   = *(const f16x8*)(vsrc + kt);
    __syncthreads();

    float p[2][4];
#pragma unroll
    for (int g = 0; g < 2; ++g) {
      const int4 mv = *(const int4*)(mrow + kt + g * 16 + l4 * 4);
      const f16x8 a0 = *(const f16x8*)&Kt[g * 16 + l15][l4 * 8];
      const f16x8 a1 = *(const f16x8*)&Kt[g * 16 + l15][32 + l4 * 8];
      f32x4 S = __builtin_amdgcn_mfma_f32_16x16x32_f16(
          a0, bq0, (f32x4){0.f, 0.f, 0.f, 0.f}, 0, 0, 0);
      S = __builtin_amdgcn_mfma_f32_16x16x32_f16(a1, bq1, S, 0, 0, 0);
      p[g][0] = __expf(mv.x ? 1e-9f : S[0] * 0.125f);
      p[g][1] = __expf(mv.y ? 1e-9f : S[1] * 0.125f);
      p[g][2] = __expf(mv.z ? 1e-9f : S[2] * 0.125f);
      p[g][3] = __expf(mv.w ? 1e-9f : S[3] * 0.125f);
      unsigned int pk0 =
          (unsigned)hbits(p[g][0]) | ((unsigned)hbits(p[g][1]) << 16);
      unsigned int pk1 =
          (unsigned)hbits(p[g][2]) | ((unsigned)hbits(p[g][3]) << 16);
      unsigned int* dst = (unsigned int*)&Pl[w][l15][g * 16 + l4 * 4];
      dst[0] = pk0;
      dst[1] = pk1;
    }
    float ps = ((p[0][0] + p[0][1]) + (p[0][2] + p[0][3])) +
               ((p[1][0] + p[1][1]) + (p[1][2] + p[1][3]));
    ps += __shfl_xor(ps, 16);
    ps += __shfl_xor(ps, 32);
    lsum += ps;

    const f16x8 pa = *(const f16x8*)&Pl[w][l15][l4 * 8];
#pragma unroll
    for (int dg = 0; dg < 4; ++dg) {
      const f16x8 vb = *(const f16x8*)&Vt[dg * 16 + l15][l4 * 8];
      acc[dg] = __builtin_amdgcn_mfma_f32_16x16x32_f16(pa, vb, acc[dg], 0, 0, 0);
    }
    __syncthreads();
  }

  if (l4 == 0) Ll[w][l15] = lsum;
  __syncthreads();

#pragma unroll
  for (int r = 0; r < 4; ++r) {
    const float inv = 1.0f / Ll[w][l4 * 4 + r];
    const int tok = b * SS + q0 + l4 * 4 + r;
    f16* op = aout + (size_t)tok * EE + h * 64 + l15;
#pragma unroll
    for (int dg = 0; dg < 4; ++dg) op[dg * 16] = (f16)(acc[dg][r] * inv);
  }
}

// ---------------------------------------------------------------------------
extern "C" void kernel_launch(void* const* d_in, const int* in_sizes, int n_in,
                              void* d_out, int out_size, void* d_ws,
                              size_t ws_size, hipStream_t stream)
{
  (void)in_sizes; (void)n_in; (void)out_size; (void)ws_size;
  const float* x   = (const float*)d_in[0];
  const int* mask  = (const int*)d_in[1];   // jnp bool staged as int32
  const float* wk  = (const float*)d_in[2];
  const float* wb  = (const float*)d_in[3];
  const float* fck = (const float*)d_in[4];
  const float* fcb = (const float*)d_in[5];
  float* out       = (float*)d_out;

  char* ws = (char*)d_ws;
  size_t off = 0;
  f16* xh    = (f16*)(ws + off); off += (size_t)4096 * 1024 * 2;  //  8.4 MB
  f16* Wt    = (f16*)(ws + off); off += (size_t)3072 * 1024 * 2;  //  6.3 MB
  f16* fckT  = (f16*)(ws + off); off += (size_t)1024 * 1024 * 2;  //  2.1 MB
  f16* qk    = (f16*)(ws + off); off += (size_t)4096 * 2048 * 2;  // 16.8 MB
  f16* vT    = (f16*)(ws + off); off += (size_t)BB * HH * 64 * SS * 2; // 8.4 MB
  f16* aoutH = (f16*)(ws + off); off += (size_t)4096 * 1024 * 2;  //  8.4 MB

  // prep: fp16 conversions / transposes
  cvt_f32_f16<<<4096 * 1024 / (8 * 256), 256, 0, stream>>>(x, xh, 4096 * 1024);
  transpose_cvt<<<dim3(3072 / 64, 1024 / 64), 256, 0, stream>>>(wk, Wt, 1024, 3072);
  transpose_cvt<<<dim3(1024 / 64, 1024 / 64), 256, 0, stream>>>(fck, fckT, 1024, 1024);

  // qkv = x @ w_kernel + w_bias  (MFMA fp16) -> qk f16 + vT f16
  gemm_f16<<<dim3(3072 / 128, 4096 / 128), 256, 0, stream>>>(
      xh, Wt, wb, 4096, 3072, 1024, 0, qk, vT, nullptr);

  // fused masked-softmax attention -> aoutH f16 [token][1024]
  attn_mfma<<<dim3(SS / 64, BB * HH), 256, 0, stream>>>(qk, vT, mask, aoutH);

  // out = aout @ fc_kernel + fc_bias  (MFMA fp16, fp32 out)
  gemm_f16<<<dim3(1024 / 128, 4096 / 128), 256, 0, stream>>>(
      aoutH, fckT, fcb, 4096, 1024, 1024, 1, nullptr, nullptr, out);
}

// Round 5
// 243.632 us; speedup vs baseline: 6.5027x; 1.1970x over previous
//
#include <hip/hip_runtime.h>
#include <math.h>

#define BB 2
#define SS 2048
#define EE 1024
#define HH 16

typedef _Float16 f16;
typedef __attribute__((ext_vector_type(8))) _Float16 f16x8;
typedef __attribute__((ext_vector_type(4))) _Float16 f16x4;
typedef __attribute__((ext_vector_type(4))) float f32x4;

// ---------------------------------------------------------------------------
// fp32 -> fp16 elementwise (n % 8 == 0)
// ---------------------------------------------------------------------------
__global__ __launch_bounds__(256) void cvt_f32_f16(
    const float* __restrict__ in, f16* __restrict__ out, int n)
{
  int i = (blockIdx.x * 256 + threadIdx.x) * 8;
  if (i >= n) return;
  float4 a = *(const float4*)(in + i);
  float4 b = *(const float4*)(in + i + 4);
  f16x8 o;
  o[0] = (f16)a.x; o[1] = (f16)a.y; o[2] = (f16)a.z; o[3] = (f16)a.w;
  o[4] = (f16)b.x; o[5] = (f16)b.y; o[6] = (f16)b.z; o[7] = (f16)b.w;
  *(f16x8*)(out + i) = o;
}

// ---------------------------------------------------------------------------
// out[n][k] = (f16) in[k][n]   (K x N fp32 -> N x K fp16), 64x64 LDS tiles
// ---------------------------------------------------------------------------
__global__ __launch_bounds__(256) void transpose_cvt(
    const float* __restrict__ in, f16* __restrict__ out, int K, int N)
{
  __shared__ float T[64][65];
  const int k0 = blockIdx.y * 64, n0 = blockIdx.x * 64;
  const int tr = threadIdx.x >> 4, tc = (threadIdx.x & 15) * 4;
#pragma unroll
  for (int i = 0; i < 4; ++i) {
    int r = tr + i * 16;
    *(float4*)&T[r][tc] = *(const float4*)(in + (size_t)(k0 + r) * N + n0 + tc);
  }
  __syncthreads();
#pragma unroll
  for (int i = 0; i < 4; ++i) {
    int nl = tr + i * 16;
    f16x4 v;
    v[0] = (f16)T[tc + 0][nl];
    v[1] = (f16)T[tc + 1][nl];
    v[2] = (f16)T[tc + 2][nl];
    v[3] = (f16)T[tc + 3][nl];
    *(f16x4*)(out + (size_t)(n0 + nl) * K + k0 + tc) = v;
  }
}

// ---------------------------------------------------------------------------
// Pack int32 bool mask -> bitmask (bit set = masked). 64 ints -> 1 u64.
// ---------------------------------------------------------------------------
__global__ __launch_bounds__(256) void pack_mask(
    const int* __restrict__ m, unsigned long long* __restrict__ bits)
{
  const int i = blockIdx.x * 256 + threadIdx.x;
  const unsigned long long bal = __ballot(m[i] != 0);
  if ((threadIdx.x & 63) == 0) bits[i >> 6] = bal;
}

// ---------------------------------------------------------------------------
// MFMA fp16 GEMM: C[M][N] = A[M][K] @ Bt[N][K]^T + bias.  (unchanged)
// ---------------------------------------------------------------------------
__global__ __launch_bounds__(256) void gemm_f16(
    const f16* __restrict__ A, const f16* __restrict__ Bt,
    const float* __restrict__ bias, int M, int N, int K, int mode,
    f16* __restrict__ oQK, f16* __restrict__ oVT, float* __restrict__ oF32)
{
  __shared__ f16 Ah[128][36];
  __shared__ f16 Bh[128][36];

  const int t = threadIdx.x;
  const int l = t & 63, w = t >> 6;
  const int l15 = l & 15, l4 = l >> 4;
  const int wr = w >> 1, wc = w & 1;
  const int n0 = blockIdx.x * 128, m0 = blockIdx.y * 128;

  const int srow = t >> 1, soff = (t & 1) * 16;
  const f16* Ap = A + (size_t)(m0 + srow) * K + soff;
  const f16* Bp = Bt + (size_t)(n0 + srow) * K + soff;

  f32x4 acc[4][4] = {};

  f16x8 ra0 = *(const f16x8*)(Ap);
  f16x8 ra1 = *(const f16x8*)(Ap + 8);
  f16x8 rb0 = *(const f16x8*)(Bp);
  f16x8 rb1 = *(const f16x8*)(Bp + 8);

  for (int k0 = 0; k0 < K; k0 += 32) {
    __syncthreads();
    *(f16x8*)&Ah[srow][soff]     = ra0;
    *(f16x8*)&Ah[srow][soff + 8] = ra1;
    *(f16x8*)&Bh[srow][soff]     = rb0;
    *(f16x8*)&Bh[srow][soff + 8] = rb1;
    __syncthreads();
    if (k0 + 32 < K) {
      ra0 = *(const f16x8*)(Ap + k0 + 32);
      ra1 = *(const f16x8*)(Ap + k0 + 40);
      rb0 = *(const f16x8*)(Bp + k0 + 32);
      rb1 = *(const f16x8*)(Bp + k0 + 40);
    }
    f16x8 af[4], bf[4];
#pragma unroll
    for (int mr = 0; mr < 4; ++mr)
      af[mr] = *(const f16x8*)&Ah[wr * 64 + mr * 16 + l15][l4 * 8];
#pragma unroll
    for (int nr = 0; nr < 4; ++nr)
      bf[nr] = *(const f16x8*)&Bh[wc * 64 + nr * 16 + l15][l4 * 8];
#pragma unroll
    for (int mr = 0; mr < 4; ++mr)
#pragma unroll
      for (int nr = 0; nr < 4; ++nr)
        acc[mr][nr] = __builtin_amdgcn_mfma_f32_16x16x32_f16(
            af[mr], bf[nr], acc[mr][nr], 0, 0, 0);
  }

  if (mode == 1) {
#pragma unroll
    for (int nr = 0; nr < 4; ++nr) {
      const int n = n0 + wc * 64 + nr * 16 + l15;
      const float bv = bias[n];
#pragma unroll
      for (int mr = 0; mr < 4; ++mr)
#pragma unroll
        for (int j = 0; j < 4; ++j) {
          const int m = m0 + wr * 64 + mr * 16 + l4 * 4 + j;
          oF32[(size_t)m * N + n] = acc[mr][nr][j] + bv;
        }
    }
  } else {
#pragma unroll
    for (int nr = 0; nr < 4; ++nr) {
      const int n = n0 + wc * 64 + nr * 16 + l15;
      const float bv = bias[n];
      if (n < 2048) {
#pragma unroll
        for (int mr = 0; mr < 4; ++mr)
#pragma unroll
          for (int j = 0; j < 4; ++j) {
            const int m = m0 + wr * 64 + mr * 16 + l4 * 4 + j;
            oQK[(size_t)m * 2048 + n] = (f16)(acc[mr][nr][j] + bv);
          }
      } else {
        const int hh = (n - 2048) >> 6;
        const int d = (n - 2048) & 63;
#pragma unroll
        for (int mr = 0; mr < 4; ++mr) {
          const int tok0 = m0 + wr * 64 + mr * 16 + l4 * 4;
          const int bq = tok0 >> 11, sq = tok0 & 2047;
          f16x4 v;
          v[0] = (f16)(acc[mr][nr][0] + bv);
          v[1] = (f16)(acc[mr][nr][1] + bv);
          v[2] = (f16)(acc[mr][nr][2] + bv);
          v[3] = (f16)(acc[mr][nr][3] + bv);
          *(f16x4*)(oVT + ((size_t)(bq * 16 + hh) * 64 + d) * SS + sq) = v;
        }
      }
    }
  }
}

// ---------------------------------------------------------------------------
// MFMA attention v2. Grid (16, 32); 256 thr = 4 waves x 32 q-rows (128/blk).
// KVBLK=64, double-buffered XOR-swizzled LDS, 1 barrier/iter.
// Swapped QK^T (mfma(K,Q), 16x16x32); P stays in regs; PV via 16x16x16
// (A-frag k-grouping of 4 == QK C-row grouping). Mask from packed bits.
// No max-subtraction; masked p = exp(1e-9) = 1.0f exactly.
// ---------------------------------------------------------------------------
__global__ __launch_bounds__(256, 2) void attn_mfma(
    const f16* __restrict__ qkbuf, const f16* __restrict__ vT,
    const unsigned long long* __restrict__ mbits, f16* __restrict__ aout)
{
  __shared__ f16 Kds[2][64 * 64];   // [key][d], rows XOR-swizzled
  __shared__ f16 Vds[2][64 * 64];   // [d][key], rows XOR-swizzled

  const int t = threadIdx.x;
  const int w = t >> 6, l = t & 63, l15 = l & 15, l4 = l >> 4;
  const int bh = blockIdx.y, b = bh >> 4, h = bh & 15;
  const int qbase = blockIdx.x * 128 + w * 32;

  // Q fragments: 2 q-sets x 2 d-halves
  f16x8 q00, q01, q10, q11;
  {
    const size_t r0 = (size_t)(b * SS + qbase + l15) * 2048 + h * 64;
    const size_t r1 = (size_t)(b * SS + qbase + 16 + l15) * 2048 + h * 64;
    q00 = *(const f16x8*)(qkbuf + r0 + l4 * 8);
    q01 = *(const f16x8*)(qkbuf + r0 + 32 + l4 * 8);
    q10 = *(const f16x8*)(qkbuf + r1 + l4 * 8);
    q11 = *(const f16x8*)(qkbuf + r1 + 32 + l4 * 8);
  }

  f32x4 accA[4] = {}, accB[4] = {};
  float lsA = 0.f, lsB = 0.f;

  const unsigned long long* mA = mbits + (size_t)(b * SS + qbase + l15) * 32;
  const unsigned long long* mB = mbits + (size_t)(b * SS + qbase + 16 + l15) * 32;

  // staging: thread t covers K rows {srow, srow+32} (16B each) and same for V
  const int srow = t >> 3;              // 0..31
  const int scb  = (t & 7) * 8;         // elem col 0..56
  const int sws  = (srow & 7) << 3;     // (srow+32)&7 == srow&7
  const f16* kb = qkbuf + (size_t)b * SS * 2048 + 1024 + h * 64 + scb;
  const f16* vb = vT + ((size_t)bh * 64 + srow) * SS + scb;

  f16x8 kr0, kr1, vr0, vr1;
#define LOADT(kt)                                                         \
  {                                                                       \
    kr0 = *(const f16x8*)(kb + (size_t)((kt) + srow) * 2048);             \
    kr1 = *(const f16x8*)(kb + (size_t)((kt) + srow + 32) * 2048);        \
    vr0 = *(const f16x8*)(vb + (kt));                                     \
    vr1 = *(const f16x8*)(vb + 32 * SS + (kt));                           \
  }
#define COMMIT(bi)                                                        \
  {                                                                       \
    *(f16x8*)&Kds[bi][srow * 64 + (scb ^ sws)]        = kr0;              \
    *(f16x8*)&Kds[bi][(srow + 32) * 64 + (scb ^ sws)] = kr1;              \
    *(f16x8*)&Vds[bi][srow * 64 + (scb ^ sws)]        = vr0;              \
    *(f16x8*)&Vds[bi][(srow + 32) * 64 + (scb ^ sws)] = vr1;              \
  }

  LOADT(0)
  COMMIT(0)
  LOADT(64)
  __syncthreads();

  const int swr = (l15 & 7) << 3;  // read-side swizzle (row&7 == l15&7)

  for (int tI = 0; tI < 32; ++tI) {
    const int cur = tI & 1;
    const unsigned long long mbA = mA[tI];
    const unsigned long long mbB = mB[tI];

#pragma unroll
    for (int g = 0; g < 4; ++g) {
      const f16* krow = &Kds[cur][(g * 16 + l15) * 64];
      const f16x8 k0 = *(const f16x8*)(krow + ((l4 * 8) ^ swr));
      const f16x8 k1 = *(const f16x8*)(krow + ((32 + l4 * 8) ^ swr));
      f32x4 SA = __builtin_amdgcn_mfma_f32_16x16x32_f16(
          k0, q00, (f32x4){0.f, 0.f, 0.f, 0.f}, 0, 0, 0);
      SA = __builtin_amdgcn_mfma_f32_16x16x32_f16(k1, q01, SA, 0, 0, 0);
      f32x4 SB = __builtin_amdgcn_mfma_f32_16x16x32_f16(
          k0, q10, (f32x4){0.f, 0.f, 0.f, 0.f}, 0, 0, 0);
      SB = __builtin_amdgcn_mfma_f32_16x16x32_f16(k1, q11, SB, 0, 0, 0);

      const unsigned int nibA = (unsigned int)(mbA >> (g * 16 + l4 * 4));
      const unsigned int nibB = (unsigned int)(mbB >> (g * 16 + l4 * 4));
      f16x4 paA, paB;
#pragma unroll
      for (int j = 0; j < 4; ++j) {
        const float pA = ((nibA >> j) & 1u) ? 1.0f : __expf(SA[j] * 0.125f);
        const float pB = ((nibB >> j) & 1u) ? 1.0f : __expf(SB[j] * 0.125f);
        lsA += pA;
        lsB += pB;
        paA[j] = (f16)pA;
        paB[j] = (f16)pB;
      }
      // PV for this 16-key group: A-frag = paA/paB directly (k = l4*4+i)
#pragma unroll
      for (int dg = 0; dg < 4; ++dg) {
        const f16x4 vf = *(const f16x4*)&Vds[cur][(dg * 16 + l15) * 64 +
                                                  ((g * 16 + l4 * 4) ^ swr)];
        accA[dg] = __builtin_amdgcn_mfma_f32_16x16x16f16(paA, vf, accA[dg], 0, 0, 0);
        accB[dg] = __builtin_amdgcn_mfma_f32_16x16x16f16(paB, vf, accB[dg], 0, 0, 0);
      }
    }

    if (tI + 1 < 32) {
      COMMIT(cur ^ 1)
      if (tI + 2 < 32) LOADT((tI + 2) * 64)
    }
    __syncthreads();
  }

  // softmax denominators: lane holds partial for q=l15 (per set); reduce over l4
  lsA += __shfl_xor(lsA, 16);
  lsA += __shfl_xor(lsA, 32);
  lsB += __shfl_xor(lsB, 16);
  lsB += __shfl_xor(lsB, 32);

#pragma unroll
  for (int j = 0; j < 4; ++j) {
    const int qr = l4 * 4 + j;
    const float invA = 1.0f / __shfl(lsA, qr);
    const float invB = 1.0f / __shfl(lsB, qr);
    const size_t rowA = (size_t)(b * SS + qbase + qr) * EE + h * 64 + l15;
    const size_t rowB = (size_t)(b * SS + qbase + 16 + qr) * EE + h * 64 + l15;
#pragma unroll
    for (int dg = 0; dg < 4; ++dg) {
      aout[rowA + dg * 16] = (f16)(accA[dg][j] * invA);
      aout[rowB + dg * 16] = (f16)(accB[dg][j] * invB);
    }
  }
}

// ---------------------------------------------------------------------------
extern "C" void kernel_launch(void* const* d_in, const int* in_sizes, int n_in,
                              void* d_out, int out_size, void* d_ws,
                              size_t ws_size, hipStream_t stream)
{
  (void)in_sizes; (void)n_in; (void)out_size; (void)ws_size;
  const float* x   = (const float*)d_in[0];
  const int* mask  = (const int*)d_in[1];   // jnp bool staged as int32
  const float* wk  = (const float*)d_in[2];
  const float* wb  = (const float*)d_in[3];
  const float* fck = (const float*)d_in[4];
  const float* fcb = (const float*)d_in[5];
  float* out       = (float*)d_out;

  char* ws = (char*)d_ws;
  size_t off = 0;
  f16* xh    = (f16*)(ws + off); off += (size_t)4096 * 1024 * 2;  //  8.4 MB
  f16* Wt    = (f16*)(ws + off); off += (size_t)3072 * 1024 * 2;  //  6.3 MB
  f16* fckT  = (f16*)(ws + off); off += (size_t)1024 * 1024 * 2;  //  2.1 MB
  f16* qk    = (f16*)(ws + off); off += (size_t)4096 * 2048 * 2;  // 16.8 MB
  f16* vT    = (f16*)(ws + off); off += (size_t)BB * HH * 64 * SS * 2; // 8.4 MB
  f16* aoutH = (f16*)(ws + off); off += (size_t)4096 * 1024 * 2;  //  8.4 MB
  unsigned long long* mbits = (unsigned long long*)(ws + off);
  off += (size_t)BB * SS * SS / 8;                                //  1.0 MB

  // prep
  cvt_f32_f16<<<4096 * 1024 / (8 * 256), 256, 0, stream>>>(x, xh, 4096 * 1024);
  transpose_cvt<<<dim3(3072 / 64, 1024 / 64), 256, 0, stream>>>(wk, Wt, 1024, 3072);
  transpose_cvt<<<dim3(1024 / 64, 1024 / 64), 256, 0, stream>>>(fck, fckT, 1024, 1024);
  pack_mask<<<BB * SS * SS / 256, 256, 0, stream>>>(mask, mbits);

  // qkv = x @ w_kernel + w_bias  (MFMA fp16) -> qk f16 + vT f16
  gemm_f16<<<dim3(3072 / 128, 4096 / 128), 256, 0, stream>>>(
      xh, Wt, wb, 4096, 3072, 1024, 0, qk, vT, nullptr);

  // fused masked-softmax attention -> aoutH f16 [token][1024]
  attn_mfma<<<dim3(SS / 128, BB * HH), 256, 0, stream>>>(qk, vT, mbits, aoutH);

  // out = aout @ fc_kernel + fc_bias  (MFMA fp16, fp32 out)
  gemm_f16<<<dim3(1024 / 128, 4096 / 128), 256, 0, stream>>>(
      aoutH, fckT, fcb, 4096, 1024, 1024, 1, nullptr, nullptr, out);
}

// Round 6
// 240.222 us; speedup vs baseline: 6.5950x; 1.0142x over previous
//
#include <hip/hip_runtime.h>
#include <math.h>

#define BB 2
#define SS 2048
#define EE 1024
#define HH 16

typedef _Float16 f16;
typedef __attribute__((ext_vector_type(8))) _Float16 f16x8;
typedef __attribute__((ext_vector_type(4))) _Float16 f16x4;
typedef __attribute__((ext_vector_type(2))) _Float16 f16x2;
typedef __attribute__((ext_vector_type(4))) float f32x4;

union P8 { f16x8 v8; f16x2 h2[4]; };
union V8 { f16x8 v8; f16x4 v4[2]; };

// 0.125 (1/sqrt(D)) * log2(e)  -- folded into Q at the GEMM1 epilogue
#define QSCALE 0.18033688011112042f

#if __has_builtin(__builtin_amdgcn_exp2f)
#define EXP2(x) __builtin_amdgcn_exp2f(x)
#else
#define EXP2(x) exp2f(x)
#endif

static __device__ __forceinline__ f16x2 pk2(float a, float b) {
#if __has_builtin(__builtin_amdgcn_cvt_pkrtz)
  return __builtin_bit_cast(f16x2, __builtin_amdgcn_cvt_pkrtz(a, b));
#else
  f16x2 r; r[0] = (f16)a; r[1] = (f16)b; return r;
#endif
}

// async global->LDS, 16B per lane; dest = wave-uniform base + lane*16
static __device__ __forceinline__ void gl16(const void* g, void* l) {
  __builtin_amdgcn_global_load_lds(
      (const __attribute__((address_space(1))) void*)g,
      (__attribute__((address_space(3))) void*)l, 16, 0, 0);
}

// ---------------------------------------------------------------------------
// fp32 -> fp16 elementwise (n % 8 == 0)
// ---------------------------------------------------------------------------
__global__ __launch_bounds__(256) void cvt_f32_f16(
    const float* __restrict__ in, f16* __restrict__ out, int n)
{
  int i = (blockIdx.x * 256 + threadIdx.x) * 8;
  if (i >= n) return;
  float4 a = *(const float4*)(in + i);
  float4 b = *(const float4*)(in + i + 4);
  f16x8 o;
  o[0] = (f16)a.x; o[1] = (f16)a.y; o[2] = (f16)a.z; o[3] = (f16)a.w;
  o[4] = (f16)b.x; o[5] = (f16)b.y; o[6] = (f16)b.z; o[7] = (f16)b.w;
  *(f16x8*)(out + i) = o;
}

// ---------------------------------------------------------------------------
// out[n][k] = (f16) in[k][n]   (K x N fp32 -> N x K fp16), 64x64 LDS tiles
// ---------------------------------------------------------------------------
__global__ __launch_bounds__(256) void transpose_cvt(
    const float* __restrict__ in, f16* __restrict__ out, int K, int N)
{
  __shared__ float T[64][65];
  const int k0 = blockIdx.y * 64, n0 = blockIdx.x * 64;
  const int tr = threadIdx.x >> 4, tc = (threadIdx.x & 15) * 4;
#pragma unroll
  for (int i = 0; i < 4; ++i) {
    int r = tr + i * 16;
    *(float4*)&T[r][tc] = *(const float4*)(in + (size_t)(k0 + r) * N + n0 + tc);
  }
  __syncthreads();
#pragma unroll
  for (int i = 0; i < 4; ++i) {
    int nl = tr + i * 16;
    f16x4 v;
    v[0] = (f16)T[tc + 0][nl];
    v[1] = (f16)T[tc + 1][nl];
    v[2] = (f16)T[tc + 2][nl];
    v[3] = (f16)T[tc + 3][nl];
    *(f16x4*)(out + (size_t)(n0 + nl) * K + k0 + tc) = v;
  }
}

// ---------------------------------------------------------------------------
// Pack int32 bool mask -> bitmask (bit set = masked). 64 ints -> 1 u64.
// ---------------------------------------------------------------------------
__global__ __launch_bounds__(256) void pack_mask(
    const int* __restrict__ m, unsigned long long* __restrict__ bits)
{
  const int i = blockIdx.x * 256 + threadIdx.x;
  const unsigned long long bal = __ballot(m[i] != 0);
  if ((threadIdx.x & 63) == 0) bits[i >> 6] = bal;
}

// ---------------------------------------------------------------------------
// MFMA fp16 GEMM, m97 structure: 128x128 tile, BK=32, global_load_lds w16
// staging into linear LDS with both-sides XOR chunk swizzle.
// mode 0: qkv epilogue (Q cols pre-scaled by QSCALE; K cols raw; V -> vT).
// mode 1: fp32 out + bias.
// ---------------------------------------------------------------------------
__global__ __launch_bounds__(256) void gemm_f16(
    const f16* __restrict__ A, const f16* __restrict__ Bt,
    const float* __restrict__ bias, int M, int N, int K, int mode,
    f16* __restrict__ oQK, f16* __restrict__ oVT, float* __restrict__ oF32)
{
  __shared__ f16 Ah[128 * 32];
  __shared__ f16 Bh[128 * 32];

  const int t = threadIdx.x;
  const int l = t & 63, w = t >> 6;
  const int l15 = l & 15, l4 = l >> 4;
  const int wr = w >> 1, wc = w & 1;
  const int n0 = blockIdx.x * 128, m0 = blockIdx.y * 128;

  // staging: wave w covers rows [w*32, w*32+32) of both A and B tiles.
  // lane l -> row_in_16 = l>>2, phys chunk (l&3); source chunk preswizzled.
  const int srow = l >> 2;
  const int gch  = (l & 3) ^ (srow & 3);
  const f16* Ap0 = A + (size_t)(m0 + w * 32 + srow) * K + gch * 8;
  const f16* Ap1 = Ap0 + (size_t)16 * K;
  const f16* Bp0 = Bt + (size_t)(n0 + w * 32 + srow) * K + gch * 8;
  const f16* Bp1 = Bp0 + (size_t)16 * K;
  f16* ldsA0 = &Ah[(w * 32) * 32];
  f16* ldsA1 = &Ah[(w * 32 + 16) * 32];
  f16* ldsB0 = &Bh[(w * 32) * 32];
  f16* ldsB1 = &Bh[(w * 32 + 16) * 32];

  f32x4 acc[4][4] = {};
  const int csw = (l15 & 3);  // read-side chunk swizzle (row&3 == l15&3)

  for (int k0 = 0; k0 < K; k0 += 32) {
    gl16(Ap0 + k0, ldsA0);
    gl16(Ap1 + k0, ldsA1);
    gl16(Bp0 + k0, ldsB0);
    gl16(Bp1 + k0, ldsB1);
    __syncthreads();   // drains vmcnt(0): DMA complete for all waves

    f16x8 af[4], bf[4];
#pragma unroll
    for (int mr = 0; mr < 4; ++mr) {
      const int row = wr * 64 + mr * 16 + l15;
      af[mr] = *(const f16x8*)&Ah[row * 32 + ((l4 ^ csw) * 8)];
    }
#pragma unroll
    for (int nr = 0; nr < 4; ++nr) {
      const int row = wc * 64 + nr * 16 + l15;
      bf[nr] = *(const f16x8*)&Bh[row * 32 + ((l4 ^ csw) * 8)];
    }
#pragma unroll
    for (int mr = 0; mr < 4; ++mr)
#pragma unroll
      for (int nr = 0; nr < 4; ++nr)
        acc[mr][nr] = __builtin_amdgcn_mfma_f32_16x16x32_f16(
            af[mr], bf[nr], acc[mr][nr], 0, 0, 0);
    __syncthreads();   // tile consumed; safe to restage
  }

  if (mode == 1) {
#pragma unroll
    for (int nr = 0; nr < 4; ++nr) {
      const int n = n0 + wc * 64 + nr * 16 + l15;
      const float bv = bias[n];
#pragma unroll
      for (int mr = 0; mr < 4; ++mr)
#pragma unroll
        for (int j = 0; j < 4; ++j) {
          const int m = m0 + wr * 64 + mr * 16 + l4 * 4 + j;
          oF32[(size_t)m * N + n] = acc[mr][nr][j] + bv;
        }
    }
  } else {
#pragma unroll
    for (int nr = 0; nr < 4; ++nr) {
      const int n = n0 + wc * 64 + nr * 16 + l15;
      const float bv = bias[n];
      if (n < 2048) {
        const float qs = (n < 1024) ? QSCALE : 1.0f;
#pragma unroll
        for (int mr = 0; mr < 4; ++mr)
#pragma unroll
          for (int j = 0; j < 4; ++j) {
            const int m = m0 + wr * 64 + mr * 16 + l4 * 4 + j;
            oQK[(size_t)m * 2048 + n] = (f16)((acc[mr][nr][j] + bv) * qs);
          }
      } else {
        const int hh = (n - 2048) >> 6;
        const int d = (n - 2048) & 63;
#pragma unroll
        for (int mr = 0; mr < 4; ++mr) {
          const int tok0 = m0 + wr * 64 + mr * 16 + l4 * 4;
          const int bq = tok0 >> 11, sq = tok0 & 2047;
          f16x4 v;
          v[0] = (f16)(acc[mr][nr][0] + bv);
          v[1] = (f16)(acc[mr][nr][1] + bv);
          v[2] = (f16)(acc[mr][nr][2] + bv);
          v[3] = (f16)(acc[mr][nr][3] + bv);
          *(f16x4*)(oVT + ((size_t)(bq * 16 + hh) * 64 + d) * SS + sq) = v;
        }
      }
    }
  }
}

// ---------------------------------------------------------------------------
// MFMA attention v3. Grid (16, 32); 256 thr = 4 waves x 32 q-rows.
// Q pre-scaled by 0.125*log2(e) -> p = exp2(S) (one TRANS op/element).
// PV via 16x16x32 with permuted key axis; softmax denom via ones-MFMA.
// Masked p = 1.0 exactly (quirk: score 1e-9, exp->1).
// ---------------------------------------------------------------------------
__global__ __launch_bounds__(256, 2) void attn_mfma(
    const f16* __restrict__ qkbuf, const f16* __restrict__ vT,
    const unsigned long long* __restrict__ mbits, f16* __restrict__ aout)
{
  __shared__ f16 Kds[2][64 * 64];   // [key][d], chunk-swizzled
  __shared__ f16 Vds[2][64 * 64];   // [d][key], chunk-swizzled

  const int t = threadIdx.x;
  const int w = t >> 6, l = t & 63, l15 = l & 15, l4 = l >> 4;
  const int bh = blockIdx.y, b = bh >> 4, h = bh & 15;
  const int qbase = blockIdx.x * 128 + w * 32;

  f16x8 q00, q01, q10, q11;
  {
    const size_t r0 = (size_t)(b * SS + qbase + l15) * 2048 + h * 64;
    const size_t r1 = (size_t)(b * SS + qbase + 16 + l15) * 2048 + h * 64;
    q00 = *(const f16x8*)(qkbuf + r0 + l4 * 8);
    q01 = *(const f16x8*)(qkbuf + r0 + 32 + l4 * 8);
    q10 = *(const f16x8*)(qkbuf + r1 + l4 * 8);
    q11 = *(const f16x8*)(qkbuf + r1 + 32 + l4 * 8);
  }

  f32x4 accA[4] = {}, accB[4] = {};
  f32x4 accLA = {}, accLB = {};
  f16x8 ones;
#pragma unroll
  for (int i = 0; i < 8; ++i) ones[i] = (f16)1.0f;

  const unsigned long long* mA = mbits + (size_t)(b * SS + qbase + l15) * 32;
  const unsigned long long* mB = mbits + (size_t)(b * SS + qbase + 16 + l15) * 32;

  const int srow = t >> 3;              // 0..31
  const int scb  = (t & 7) * 8;
  const int sws  = (srow & 7) << 3;
  const f16* kb = qkbuf + (size_t)b * SS * 2048 + 1024 + h * 64 + scb;
  const f16* vb = vT + ((size_t)bh * 64 + srow) * SS + scb;

  f16x8 kr0, kr1, vr0, vr1;
#define LOADT(kt)                                                         \
  {                                                                       \
    kr0 = *(const f16x8*)(kb + (size_t)((kt) + srow) * 2048);             \
    kr1 = *(const f16x8*)(kb + (size_t)((kt) + srow + 32) * 2048);        \
    vr0 = *(const f16x8*)(vb + (kt));                                     \
    vr1 = *(const f16x8*)(vb + 32 * SS + (kt));                           \
  }
#define COMMIT(bi)                                                        \
  {                                                                       \
    *(f16x8*)&Kds[bi][srow * 64 + (scb ^ sws)]        = kr0;              \
    *(f16x8*)&Kds[bi][(srow + 32) * 64 + (scb ^ sws)] = kr1;              \
    *(f16x8*)&Vds[bi][srow * 64 + (scb ^ sws)]        = vr0;              \
    *(f16x8*)&Vds[bi][(srow + 32) * 64 + (scb ^ sws)] = vr1;              \
  }

  LOADT(0)
  COMMIT(0)
  LOADT(64)
  __syncthreads();

  const int swr = (l15 & 7) << 3;  // read-side swizzle (row&7 == l15&7)

  unsigned long long mbA = mA[0], mbB = mB[0];

  for (int tI = 0; tI < 32; ++tI) {
    const int cur = tI & 1;
    unsigned long long nmbA = 0, nmbB = 0;
    if (tI + 1 < 32) { nmbA = mA[tI + 1]; nmbB = mB[tI + 1]; }

#pragma unroll
    for (int sg = 0; sg < 2; ++sg) {
      float pA[8], pB[8];
#pragma unroll
      for (int gh = 0; gh < 2; ++gh) {
        const int g = sg * 2 + gh;
        const f16* krow = &Kds[cur][(g * 16 + l15) * 64];
        const f16x8 k0 = *(const f16x8*)(krow + ((l4 * 8) ^ swr));
        const f16x8 k1 = *(const f16x8*)(krow + ((32 + l4 * 8) ^ swr));
        f32x4 SA = __builtin_amdgcn_mfma_f32_16x16x32_f16(
            k0, q00, (f32x4){0.f, 0.f, 0.f, 0.f}, 0, 0, 0);
        SA = __builtin_amdgcn_mfma_f32_16x16x32_f16(k1, q01, SA, 0, 0, 0);
        f32x4 SB = __builtin_amdgcn_mfma_f32_16x16x32_f16(
            k0, q10, (f32x4){0.f, 0.f, 0.f, 0.f}, 0, 0, 0);
        SB = __builtin_amdgcn_mfma_f32_16x16x32_f16(k1, q11, SB, 0, 0, 0);

        const unsigned int nibA = (unsigned int)(mbA >> (g * 16 + l4 * 4));
        const unsigned int nibB = (unsigned int)(mbB >> (g * 16 + l4 * 4));
#pragma unroll
        for (int j = 0; j < 4; ++j) {
          pA[gh * 4 + j] = ((nibA >> j) & 1u) ? 1.0f : EXP2(SA[j]);
          pB[gh * 4 + j] = ((nibB >> j) & 1u) ? 1.0f : EXP2(SB[j]);
        }
      }
      P8 uA, uB;
      uA.h2[0] = pk2(pA[0], pA[1]); uA.h2[1] = pk2(pA[2], pA[3]);
      uA.h2[2] = pk2(pA[4], pA[5]); uA.h2[3] = pk2(pA[6], pA[7]);
      uB.h2[0] = pk2(pB[0], pB[1]); uB.h2[1] = pk2(pB[2], pB[3]);
      uB.h2[2] = pk2(pB[4], pB[5]); uB.h2[3] = pk2(pB[6], pB[7]);

#pragma unroll
      for (int dg = 0; dg < 4; ++dg) {
        const f16* vrow = &Vds[cur][(dg * 16 + l15) * 64];
        V8 uv;
        uv.v4[0] = *(const f16x4*)(vrow + ((sg * 32 + l4 * 4) ^ swr));
        uv.v4[1] = *(const f16x4*)(vrow + ((sg * 32 + 16 + l4 * 4) ^ swr));
        accA[dg] = __builtin_amdgcn_mfma_f32_16x16x32_f16(uA.v8, uv.v8, accA[dg], 0, 0, 0);
        accB[dg] = __builtin_amdgcn_mfma_f32_16x16x32_f16(uB.v8, uv.v8, accB[dg], 0, 0, 0);
      }
      accLA = __builtin_amdgcn_mfma_f32_16x16x32_f16(uA.v8, ones, accLA, 0, 0, 0);
      accLB = __builtin_amdgcn_mfma_f32_16x16x32_f16(uB.v8, ones, accLB, 0, 0, 0);
    }

    if (tI + 1 < 32) {
      COMMIT(cur ^ 1)
      if (tI + 2 < 32) LOADT((tI + 2) * 64)
    }
    __syncthreads();
    mbA = nmbA; mbB = nmbB;
  }

  // accL[j] = sum_k P[q = l4*4+j][k]  (identical across l15) -> direct denom
#pragma unroll
  for (int j = 0; j < 4; ++j) {
    const int qr = l4 * 4 + j;
    const float invA = 1.0f / accLA[j];
    const float invB = 1.0f / accLB[j];
    const size_t rowA = (size_t)(b * SS + qbase + qr) * EE + h * 64 + l15;
    const size_t rowB = (size_t)(b * SS + qbase + 16 + qr) * EE + h * 64 + l15;
#pragma unroll
    for (int dg = 0; dg < 4; ++dg) {
      aout[rowA + dg * 16] = (f16)(accA[dg][j] * invA);
      aout[rowB + dg * 16] = (f16)(accB[dg][j] * invB);
    }
  }
}

// ---------------------------------------------------------------------------
extern "C" void kernel_launch(void* const* d_in, const int* in_sizes, int n_in,
                              void* d_out, int out_size, void* d_ws,
                              size_t ws_size, hipStream_t stream)
{
  (void)in_sizes; (void)n_in; (void)out_size; (void)ws_size;
  const float* x   = (const float*)d_in[0];
  const int* mask  = (const int*)d_in[1];   // jnp bool staged as int32
  const float* wk  = (const float*)d_in[2];
  const float* wb  = (const float*)d_in[3];
  const float* fck = (const float*)d_in[4];
  const float* fcb = (const float*)d_in[5];
  float* out       = (float*)d_out;

  char* ws = (char*)d_ws;
  size_t off = 0;
  f16* xh    = (f16*)(ws + off); off += (size_t)4096 * 1024 * 2;  //  8.4 MB
  f16* Wt    = (f16*)(ws + off); off += (size_t)3072 * 1024 * 2;  //  6.3 MB
  f16* fckT  = (f16*)(ws + off); off += (size_t)1024 * 1024 * 2;  //  2.1 MB
  f16* qk    = (f16*)(ws + off); off += (size_t)4096 * 2048 * 2;  // 16.8 MB
  f16* vT    = (f16*)(ws + off); off += (size_t)BB * HH * 64 * SS * 2; // 8.4 MB
  f16* aoutH = (f16*)(ws + off); off += (size_t)4096 * 1024 * 2;  //  8.4 MB
  unsigned long long* mbits = (unsigned long long*)(ws + off);
  off += (size_t)BB * SS * SS / 8;                                //  1.0 MB

  // prep
  cvt_f32_f16<<<4096 * 1024 / (8 * 256), 256, 0, stream>>>(x, xh, 4096 * 1024);
  transpose_cvt<<<dim3(3072 / 64, 1024 / 64), 256, 0, stream>>>(wk, Wt, 1024, 3072);
  transpose_cvt<<<dim3(1024 / 64, 1024 / 64), 256, 0, stream>>>(fck, fckT, 1024, 1024);
  pack_mask<<<BB * SS * SS / 256, 256, 0, stream>>>(mask, mbits);

  // qkv = x @ w_kernel + w_bias  (MFMA fp16) -> qk f16 (Q pre-scaled) + vT f16
  gemm_f16<<<dim3(3072 / 128, 4096 / 128), 256, 0, stream>>>(
      xh, Wt, wb, 4096, 3072, 1024, 0, qk, vT, nullptr);

  // fused masked-softmax attention -> aoutH f16 [token][1024]
  attn_mfma<<<dim3(SS / 128, BB * HH), 256, 0, stream>>>(qk, vT, mbits, aoutH);

  // out = aout @ fc_kernel + fc_bias  (MFMA fp16, fp32 out)
  gemm_f16<<<dim3(1024 / 128, 4096 / 128), 256, 0, stream>>>(
      aoutH, fckT, fcb, 4096, 1024, 1024, 1, nullptr, nullptr, out);
}